// Round 16
// baseline (170.607 us; speedup 1.0000x reference)
//
#include <hip/hip_runtime.h>
#include <math.h>

// Problem constants
#define NTOT 65536   // B*H*W = 64*32*32
#define KCB  1024
#define DIM  64

typedef float fvec2 __attribute__((ext_vector_type(2)));
typedef float fvec4 __attribute__((ext_vector_type(4)));
typedef short sh8  __attribute__((ext_vector_type(8)));   // 8 bf16 = 4 VGPRs

// d_out layout (floats), concatenated return order
static const size_t OFF_Q    = 0;          // [64,64,32,32] = 4194304
static const size_t OFF_LOSS = 4194304;    // scalar
static const size_t OFF_PERP = 4194305;    // scalar
static const size_t OFF_ENC  = 4194306;    // [65536,1024] = 67108864
static const size_t OFF_EMB  = 71303170;   // [1024,64]
static const size_t OFF_NCS  = 71368706;   // [1024]
static const size_t OFF_NEMA = 71369730;   // [1024,64]

// ws layout (bytes)
static const size_t WSO_IDX   = 0;         // int[65536]
static const size_t WSO_ESQ   = 262144;    // float[1024]
static const size_t WSO_LOSSP = 266240;    // float[4096] (per-assign-block)
static const size_t WSO_CNT   = 282624;    // int[1024]
static const size_t WSO_SCAL  = 286720;    // float[8]
static const size_t WSO_EBH   = 290816;    // ushort[65536] e_hi, B-frag-major
static const size_t WSO_EBL   = 421888;    // ushort[65536] e_lo
static const size_t WSO_PDW   = 552960;    // float[16][1024][64] partial dw (4 MB)
static const size_t WSO_PCNT  = 4747264;   // int[16][1024]
static const size_t WSO_ZC    = 4812800;   // float[65536*64] (optional compact z)
static const size_t WS_NEED_ZC = 4812800 + (size_t)NTOT * DIM * 4;

// bf16 round-to-nearest-even split helpers
__device__ __forceinline__ unsigned short f2bf(float f) {
    unsigned u = __builtin_bit_cast(unsigned, f);
    return (unsigned short)((u + 0x7FFFu + ((u >> 16) & 1u)) >> 16);
}
__device__ __forceinline__ float bf2f(unsigned short h) {
    unsigned u = ((unsigned)h) << 16;
    return __builtin_bit_cast(float, u);
}

// ---------------------------------------------------------------------------
// K0: split e into bf16 hi/lo (B-frag-major) + fused e_sq via 8-lane reduce.
__global__ void k_eprep(const float* __restrict__ emb,
                        unsigned short* __restrict__ ebh,
                        unsigned short* __restrict__ ebl,
                        float* __restrict__ esq) {
    int gid = blockIdx.x * 256 + threadIdx.x;   // 32x256 = 8192
    int c = gid >> 3, ko8 = gid & 7;
    const fvec4* p = (const fvec4*)(emb + ((size_t)c << 6) + (ko8 << 3));
    fvec4 v0 = p[0], v1 = p[1];
    float f[8] = {v0.x, v0.y, v0.z, v0.w, v1.x, v1.y, v1.z, v1.w};
    sh8 h, l;
    float sq0 = 0.f, sq1 = 0.f;
#pragma unroll
    for (int j = 0; j < 8; ++j) {
        unsigned short hb = f2bf(f[j]);
        h[j] = (short)hb;
        l[j] = (short)f2bf(f[j] - bf2f(hb));
        if (j < 4) sq0 = fmaf(f[j], f[j], sq0); else sq1 = fmaf(f[j], f[j], sq1);
    }
    float sq = sq0 + sq1;
    sq += __shfl_xor(sq, 1, 64);
    sq += __shfl_xor(sq, 2, 64);
    sq += __shfl_xor(sq, 4, 64);
    if (ko8 == 0) esq[c] = sq;

    int ct = c >> 4, cl = c & 15, kc = ko8 >> 2, ko = ko8 & 3;
    size_t base = ((((size_t)ct << 1) + kc) << 9) + (((size_t)(ko << 4) + cl) << 3);
    *(sh8*)(ebh + base) = h;
    *(sh8*)(ebl + base) = l;
}

// ---------------------------------------------------------------------------
// K1: assignment, ONE-WAVE blocks (round-16). 4096 blocks x 64 threads;
// each block owns 16 rows. LDS 4.3KB + forced VGPR<=64 via
// __launch_bounds__(64,8) -> 8 waves/SIMD (2x TLP vs r11's 4). Rationale:
// r9 showed time ~doubles when TLP halves -> latency-bound; the r11
// structure was stuck at 4 waves/SIMD by LDS(33KB)+VGPR(~100) quantization.
// Depth-0 B loads: with 8 waves, TLP hides the L2 latency (duty 0.4 x 8).
__global__ __launch_bounds__(64, 8)
void k_assign(const float* __restrict__ ze, const float* __restrict__ emb,
              const float* __restrict__ esq,
              const unsigned short* __restrict__ ebh,
              const unsigned short* __restrict__ ebl,
              int* __restrict__ idx_out, float* __restrict__ lossp,
              float* __restrict__ zc, int use_zc) {
    __shared__ float zt[16 * 65];      // z tile [row][d], stride 65
    __shared__ float sm_b[16], sm_s2[16];
    __shared__ int   sm_i1[16], sm_i2[16], sfidx[16];

    const int lane = threadIdx.x;
    const int blk  = blockIdx.x;       // 4096
    const int b    = blk >> 6;
    const int hw0  = (blk & 63) << 4;  // 16 hw positions
    const int n0   = blk << 4;
    const int cg   = lane & 15;
    const int ko   = lane >> 4;

    // ---- stage z: 16 iters, wave covers 4 d-rows x 16 hw per iter ----
    {
        const int r = lane & 15;           // hw offset
        const int dq = lane >> 4;          // d sub-quad
        for (int it = 0; it < 16; ++it) {
            const int d = (it << 2) + dq;
            zt[r * 65 + d] = ze[(((size_t)(b << 6) + d) << 10) + hw0 + r];
        }
    }
    __syncthreads();

    // ---- A-fragments: row cg, k = kc*32 + ko*8 + j ----
    sh8 Ah0, Ah1, Al0, Al1;
#pragma unroll
    for (int j = 0; j < 8; ++j) {
        float f0 = zt[cg * 65 + (ko << 3) + j];
        float f1 = zt[cg * 65 + 32 + (ko << 3) + j];
        unsigned short h0 = f2bf(f0), h1 = f2bf(f1);
        Ah0[j] = (short)h0;  Al0[j] = (short)f2bf(f0 - bf2f(h0));
        Ah1[j] = (short)h1;  Al1[j] = (short)f2bf(f1 - bf2f(h1));
    }

    // ---- top-2 tracking: slot s -> row ko*4+s, col = code ----
    float tb[4]  = {3.4e38f, 3.4e38f, 3.4e38f, 3.4e38f};
    float ts2[4] = {3.4e38f, 3.4e38f, 3.4e38f, 3.4e38f};
    int ti1[4] = {0, 0, 0, 0};
    int ti2[4] = {0, 0, 0, 0};

    const int lb = lane << 3;   // ushort offset of my B-frag within a tile

    for (int i = 0; i < 64; ++i) {
        const int ct = (i + blk) & 63;              // per-block stagger
        const unsigned short* ph = ebh + ((size_t)ct << 10);
        const unsigned short* pl = ebl + ((size_t)ct << 10);
        sh8 bh0 = *(const sh8*)(ph + lb);
        sh8 bh1 = *(const sh8*)(ph + 512 + lb);
        sh8 bl0 = *(const sh8*)(pl + lb);
        sh8 bl1 = *(const sh8*)(pl + 512 + lb);
        const float es = esq[(ct << 4) + cg];

        fvec4 aa = {0.f, 0.f, 0.f, 0.f}, ab = {0.f, 0.f, 0.f, 0.f};
        aa = __builtin_amdgcn_mfma_f32_16x16x32_bf16(Ah0, bh0, aa, 0, 0, 0);
        ab = __builtin_amdgcn_mfma_f32_16x16x32_bf16(Ah1, bh1, ab, 0, 0, 0);
        aa = __builtin_amdgcn_mfma_f32_16x16x32_bf16(Ah0, bl0, aa, 0, 0, 0);
        ab = __builtin_amdgcn_mfma_f32_16x16x32_bf16(Ah1, bl1, ab, 0, 0, 0);
        aa = __builtin_amdgcn_mfma_f32_16x16x32_bf16(Al0, bh0, aa, 0, 0, 0);
        ab = __builtin_amdgcn_mfma_f32_16x16x32_bf16(Al1, bh1, ab, 0, 0, 0);
        fvec4 acc = aa + ab;

        const int code = (ct << 4) + cg;
#pragma unroll
        for (int s = 0; s < 4; ++s) {
            float sc = fmaf(acc[s], -2.0f, es);
            bool c1 = sc < tb[s];
            bool c2 = sc < ts2[s];
            ti2[s] = c1 ? ti1[s] : (c2 ? code : ti2[s]);
            ts2[s] = c1 ? tb[s] : (c2 ? sc : ts2[s]);
            ti1[s] = c1 ? code : ti1[s];
            tb[s]  = c1 ? sc : tb[s];
        }
    }

    // ---- merge across 16 cg lanes (in-wave butterfly, 4 steps) ----
#pragma unroll
    for (int s = 0; s < 4; ++s) {
#pragma unroll
        for (int st = 1; st < 16; st <<= 1) {
            float ob  = __shfl_xor(tb[s],  st, 64);
            float os2 = __shfl_xor(ts2[s], st, 64);
            int   oi1 = __shfl_xor(ti1[s], st, 64);
            int   oi2 = __shfl_xor(ti2[s], st, 64);
            if (ob < tb[s]) { ts2[s] = tb[s]; ti2[s] = ti1[s]; tb[s] = ob; ti1[s] = oi1; }
            else if (ob < ts2[s]) { ts2[s] = ob; ti2[s] = oi1; }
            if (os2 < ts2[s]) { ts2[s] = os2; ti2[s] = oi2; }
        }
    }
    if (cg == 0) {
#pragma unroll
        for (int s = 0; s < 4; ++s) {
            const int row = (ko << 2) + s;
            sm_b[row]  = tb[s];
            sm_s2[row] = ts2[s];
            sm_i1[row] = ti1[s];
            sm_i2[row] = ti2[s];
        }
    }
    __syncthreads();

    // ---- finalize: lane<16 owns row=lane; fp64 refine on near-ties ----
    if (lane < 16) {
        const int r = lane;
        int fi1 = sm_i1[r];
        if (sm_s2[r] - sm_b[r] < 2e-2f) {
            int fi2 = sm_i2[r];
            double d1 = 0.0, d2 = 0.0;
            const float* e1 = emb + (size_t)fi1 * 64;
            const float* e2 = emb + (size_t)fi2 * 64;
            for (int d = 0; d < 64; ++d) {
                double zd = (double)zt[r * 65 + d];
                double q1 = zd - (double)e1[d];
                double q2 = zd - (double)e2[d];
                d1 += q1 * q1;
                d2 += q2 * q2;
            }
            if ((d2 < d1) || (d2 == d1 && fi2 < fi1)) fi1 = fi2;
        }
        sfidx[r] = fi1;
        idx_out[n0 + r] = fi1;
    }
    __syncthreads();

    // ---- loss partial + compact z: lane -> row lane>>2, d0=(lane&3)*16 ----
    float lacc = 0.f;
    {
        const int r  = lane >> 2;
        const int d0 = (lane & 3) << 4;
        const float* er = emb + ((size_t)sfidx[r] << 6) + d0;
        float zrow[16];
#pragma unroll
        for (int j = 0; j < 16; ++j) {
            float zv = zt[r * 65 + d0 + j];
            zrow[j] = zv;
            float df = er[j] - zv;
            lacc = fmaf(df, df, lacc);
        }
        if (use_zc) {
            float* zp = zc + (((size_t)(n0 + r)) << 6) + d0;
#pragma unroll
            for (int j = 0; j < 4; ++j) {
                fvec4 v = {zrow[4*j], zrow[4*j+1], zrow[4*j+2], zrow[4*j+3]};
                *(fvec4*)(zp + (j << 2)) = v;
            }
        }
    }
    // wave reduce loss
#pragma unroll
    for (int st = 1; st < 64; st <<= 1) lacc += __shfl_xor(lacc, st, 64);
    if (lane == 0) lossp[blk] = lacc;
}

// ---------------------------------------------------------------------------
// K2: merged tail (r15). Odd blocks: output streaming. Even blocks:
// stats-partials (kg,ng decomposition, 4 barriers).
__global__ __launch_bounds__(256)
void k_tail(const int* __restrict__ idx, const float* __restrict__ zcmp,
            const float* __restrict__ ze, const float* __restrict__ emb,
            float* __restrict__ out, float* __restrict__ pdw,
            int* __restrict__ pcnt, int use_zc) {
    __shared__ __align__(16) char smem[32864];
    const int t = threadIdx.x;

    if (blockIdx.x & 1) {
        // ---------------- out role ----------------
        const int blk = blockIdx.x >> 1;
        const int b   = blk >> 4;
        const int hw0 = (blk & 15) << 6;
        const int n0  = blk << 6;
        int*   sfidx = (int*)smem;            // 64
        float* qt    = (float*)(smem + 256);  // 64*65

        if (t < 64) sfidx[t] = idx[n0 + t];
        __syncthreads();

        for (int i = t; i < 4096; i += 256) {
            int r = i >> 6, d = i & 63;
            qt[d * 65 + r] = emb[(size_t)sfidx[r] * 64 + d];
        }

        float* ebase = out + OFF_ENC;
        if (t < 255) {
            const int cb = 2 + (t << 2);
            for (int r = 0; r < 64; ++r) {
                const int fi = sfidx[r];
                fvec4 v;
                v.x = (fi == cb)     ? 1.0f : 0.0f;
                v.y = (fi == cb + 1) ? 1.0f : 0.0f;
                v.z = (fi == cb + 2) ? 1.0f : 0.0f;
                v.w = (fi == cb + 3) ? 1.0f : 0.0f;
                __builtin_nontemporal_store(
                    v, (fvec4*)(ebase + ((size_t)(n0 + r) << 10) + cb));
            }
        } else {
            for (int r = 0; r < 64; ++r) {
                const int fi = sfidx[r];
                float* rowp = ebase + ((size_t)(n0 + r) << 10);
                fvec2 hd, tl;
                hd.x = (fi == 0)    ? 1.0f : 0.0f;
                hd.y = (fi == 1)    ? 1.0f : 0.0f;
                tl.x = (fi == 1022) ? 1.0f : 0.0f;
                tl.y = (fi == 1023) ? 1.0f : 0.0f;
                __builtin_nontemporal_store(hd, (fvec2*)rowp);
                __builtin_nontemporal_store(tl, (fvec2*)(rowp + 1022));
            }
        }
        __syncthreads();

        for (int i = t; i < 4096; i += 256) {
            int d = i >> 6, r = i & 63;
            __builtin_nontemporal_store(
                qt[d * 65 + r],
                &out[OFF_Q + ((size_t)((b << 6) + d) << 10) + hw0 + r]);
        }
        return;
    }

    // ---------------- stats-partial role ----------------
    const int sidx = blockIdx.x >> 1;   // 0..1023
    const int kg   = sidx & 63;         // code group (16 codes)
    const int ng   = sidx >> 6;         // n-range (4096 entries)
    const int k0   = kg << 4;
    const int g    = t >> 6;            // lane group 0..3
    const int d    = t & 63;
    const int lane = t & 63;

    int*   s_list = (int*)smem;                    // 4096 ints
    float* part   = (float*)(smem + 16384);        // [4][16][64]
    int*   s_wsum = (int*)(smem + 32768);          // 4
    int*   s_cnt  = (int*)(smem + 32784);          // 16

    for (int i = t; i < 4096; i += 256) part[i] = 0.f;
    if (t < 16) s_cnt[t] = 0;

    const int nb = (ng << 12) + (t << 4);
    const int4* ip = (const int4*)(idx + nb);
    const int4 v0 = ip[0], v1 = ip[1], v2 = ip[2], v3 = ip[3];

#define MM(x) ((unsigned)((x) - k0) < 16u)
    int c = 0;
    c += MM(v0.x) + MM(v0.y) + MM(v0.z) + MM(v0.w);
    c += MM(v1.x) + MM(v1.y) + MM(v1.z) + MM(v1.w);
    c += MM(v2.x) + MM(v2.y) + MM(v2.z) + MM(v2.w);
    c += MM(v3.x) + MM(v3.y) + MM(v3.z) + MM(v3.w);

    int inc = c;
#pragma unroll
    for (int off = 1; off < 64; off <<= 1) {
        int y = __shfl_up(inc, (unsigned)off, 64);
        if (lane >= off) inc += y;
    }
    if (lane == 63) s_wsum[g] = inc;
    __syncthreads();                      // (A)

    int wbase = 0;
#pragma unroll
    for (int w = 0; w < 4; ++w) wbase += (w < g) ? s_wsum[w] : 0;
    const int M = s_wsum[0] + s_wsum[1] + s_wsum[2] + s_wsum[3];
    int pos = wbase + inc - c;

#define EMIT(x, o) if (MM(x)) { s_list[pos++] = (((t << 4) + (o)) << 4) | ((x) - k0); \
                                atomicAdd(&s_cnt[(x) - k0], 1); }
    EMIT(v0.x, 0)  EMIT(v0.y, 1)  EMIT(v0.z, 2)  EMIT(v0.w, 3)
    EMIT(v1.x, 4)  EMIT(v1.y, 5)  EMIT(v1.z, 6)  EMIT(v1.w, 7)
    EMIT(v2.x, 8)  EMIT(v2.y, 9)  EMIT(v2.z, 10) EMIT(v2.w, 11)
    EMIT(v3.x, 12) EMIT(v3.y, 13) EMIT(v3.z, 14) EMIT(v3.w, 15)
#undef EMIT
#undef MM
    __syncthreads();                      // (B)

#define ZL(nloc) (use_zc ? zcmp[(((size_t)((ng << 12) + (nloc))) << 6) + d] \
                         : ze[((((size_t)(((ng << 12) + (nloc)) >> 10) << 6) + d) << 10) + (((ng << 12) + (nloc)) & 1023)])
    {
        float* pg = part + (g << 10);
        int j = g;
        for (; j + 4 < M; j += 8) {
            int e0 = s_list[j], e1 = s_list[j + 4];
            float f0 = ZL(e0 >> 4);
            float f1 = ZL(e1 >> 4);
            pg[((e0 & 15) << 6) + d] += f0;
            pg[((e1 & 15) << 6) + d] += f1;
        }
        for (; j < M; j += 4) {
            int e0 = s_list[j];
            pg[((e0 & 15) << 6) + d] += ZL(e0 >> 4);
        }
    }
#undef ZL
    __syncthreads();                      // (C)

    for (int i = t; i < 1024; i += 256) {
        float s = ((part[i] + part[1024 + i]) + part[2048 + i]) + part[3072 + i];
        int cc = i >> 6, dd = i & 63;
        pdw[(((size_t)(ng << 10) + k0 + cc) << 6) + dd] = s;
    }
    if (t < 16) pcnt[(ng << 10) + k0 + t] = s_cnt[t];
}

// ---------------------------------------------------------------------------
// K3: reduce partials -> new_ema_w, new_cluster_size, counts. 256x256.
__global__ __launch_bounds__(256)
void k_red(const float* __restrict__ pdw, const int* __restrict__ pcnt,
           const float* __restrict__ emaw, const float* __restrict__ ecs,
           float* __restrict__ out, int* __restrict__ counts) {
    const int gid = blockIdx.x * 256 + threadIdx.x;   // 65536
    const int k = gid >> 6, d = gid & 63;
    float s = 0.f;
#pragma unroll
    for (int ng = 0; ng < 16; ++ng)
        s += pdw[(((size_t)(ng << 10) + k) << 6) + d];   // fixed order
    out[OFF_NEMA + ((size_t)k << 6) + d] =
        fmaf(0.01f, s, 0.99f * emaw[((size_t)k << 6) + d]);
    if (d == 0) {
        int c = 0;
#pragma unroll
        for (int ng = 0; ng < 16; ++ng) c += pcnt[(ng << 10) + k];
        counts[k] = c;
        out[OFF_NCS + k] = fmaf(0.01f, (float)c, 0.99f * ecs[k]);
    }
}

// ---------------------------------------------------------------------------
// K4a: scalars — loss (4096 partials now), n = sum(ncs), perplexity
__global__ void k_scalars(const float* __restrict__ lossp, const int* __restrict__ counts,
                          const float* __restrict__ ncs, float* __restrict__ out,
                          float* __restrict__ scal) {
    __shared__ float sr[256];
    const int t = threadIdx.x;

    float v = 0.f;
    for (int i = t; i < 4096; i += 256) v += lossp[i];   // fixed order per t
    sr[t] = v;
    __syncthreads();
    for (int s = 128; s > 0; s >>= 1) { if (t < s) sr[t] += sr[t + s]; __syncthreads(); }
    if (t == 0) out[OFF_LOSS] = sr[0] * (0.25f / 4194304.0f);
    __syncthreads();

    v = ncs[t] + ncs[t + 256] + ncs[t + 512] + ncs[t + 768];
    sr[t] = v;
    __syncthreads();
    for (int s = 128; s > 0; s >>= 1) { if (t < s) sr[t] += sr[t + s]; __syncthreads(); }
    if (t == 0) scal[0] = sr[0];
    __syncthreads();

    float pv = 0.f;
    for (int i = t; i < 1024; i += 256) {
        float p = (float)counts[i] * (1.0f / 65536.0f);
        pv += p * logf(p + 1e-10f);
    }
    sr[t] = pv;
    __syncthreads();
    for (int s = 128; s > 0; s >>= 1) { if (t < s) sr[t] += sr[t + s]; __syncthreads(); }
    if (t == 0) out[OFF_PERP] = expf(-sr[0]);
}

// ---------------------------------------------------------------------------
// K4b: new_embedding_w = new_ema_w / cluster_size
__global__ void k_embnorm(const float* __restrict__ nema, const float* __restrict__ ncs,
                          const float* __restrict__ scal, float* __restrict__ embw) {
    int i = blockIdx.x * 256 + threadIdx.x;   // 65536
    float n = scal[0];
    int k = i >> 6;
    float cs = (ncs[k] + 1e-10f) / (n + 1.024e-7f) * n;   // (ncs+EPS)/(n+K*EPS)*n
    embw[i] = nema[i] / cs;
}

// ---------------------------------------------------------------------------
extern "C" void kernel_launch(void* const* d_in, const int* in_sizes, int n_in,
                              void* d_out, int out_size, void* d_ws, size_t ws_size,
                              hipStream_t stream) {
    const float* ze   = (const float*)d_in[0];
    const float* emb  = (const float*)d_in[1];
    const float* ecs  = (const float*)d_in[2];
    const float* emaw = (const float*)d_in[3];
    float* out = (float*)d_out;
    char*  ws  = (char*)d_ws;

    int*            idx    = (int*)(ws + WSO_IDX);
    float*          esq    = (float*)(ws + WSO_ESQ);
    float*          lossp  = (float*)(ws + WSO_LOSSP);
    int*            counts = (int*)(ws + WSO_CNT);
    float*          scal   = (float*)(ws + WSO_SCAL);
    unsigned short* ebh    = (unsigned short*)(ws + WSO_EBH);
    unsigned short* ebl    = (unsigned short*)(ws + WSO_EBL);
    float*          pdw    = (float*)(ws + WSO_PDW);
    int*            pcnt   = (int*)(ws + WSO_PCNT);
    float*          zc     = (float*)(ws + WSO_ZC);
    const int use_zc = (ws_size >= WS_NEED_ZC) ? 1 : 0;

    k_eprep  <<<32,   256, 0, stream>>>(emb, ebh, ebl, esq);
    k_assign <<<4096, 64,  0, stream>>>(ze, emb, esq, ebh, ebl, idx, lossp, zc, use_zc);
    k_tail   <<<2048, 256, 0, stream>>>(idx, zc, ze, emb, out, pdw, pcnt, use_zc);
    k_red    <<<256,  256, 0, stream>>>(pdw, pcnt, emaw, ecs, out, counts);
    k_scalars<<<1,    256, 0, stream>>>(lossp, counts, out + OFF_NCS, out, scal);
    k_embnorm<<<256,  256, 0, stream>>>(out + OFF_NEMA, out + OFF_NCS, scal, out + OFF_EMB);
}